// Round 7
// baseline (504.040 us; speedup 1.0000x reference)
//
#include <hip/hip_runtime.h>

#define TT   2048
#define DD   4096
#define NH   32
#define NKVH 8
#define HDM  128
#define KD   4096
#define NQKV 6144

typedef unsigned short u16;
typedef short v8s __attribute__((ext_vector_type(8)));
typedef float v4f __attribute__((ext_vector_type(4)));

// Q pre-scale: 1/sqrt(128) * log2(e)  (log2e folded so attn uses bare exp2)
#define QSCALE 0.12751744547734565f
// fixed softmax max: 12 * log2(e). Valid because |S| <= |q||k|/sqrt(128) = 11.32
// (RMSNorm fixes |q|=|k|=sqrt(128); RoPE is a rotation, norm-preserving).
#define EOFF   17.312340490667562f

__device__ __forceinline__ u16 f2bf(float f) {
    unsigned u = __builtin_bit_cast(unsigned, f);
    u += 0x7fffu + ((u >> 16) & 1u);   // round-to-nearest-even
    return (u16)(u >> 16);
}
__device__ __forceinline__ float bf2f(u16 h) {
    return __builtin_bit_cast(float, ((unsigned)h) << 16);
}
__device__ __forceinline__ void gl2lds16(const void* g, void* l) {
    // async global->LDS, 16B/lane; LDS dest = wave-uniform base + lane*16
    using gv = const __attribute__((address_space(1))) void;
    using lv = __attribute__((address_space(3))) void;
    __builtin_amdgcn_global_load_lds((gv*)g, (lv*)l, 16, 0, 0);
}

// -------- 64x64 transpose+cast tile: out[n][k] = bf16(in[k][n]) --------
__device__ __forceinline__ void transpose_tile64(const float* __restrict__ in,
                                                 u16* __restrict__ out,
                                                 int K, int N, int n0, int k0,
                                                 float* tile, int t) {
    int rc = t >> 4, cc = (t & 15) * 4;
#pragma unroll
    for (int p = 0; p < 4; ++p) {
        int k = p * 16 + rc;
        float4 v = *(const float4*)&in[(size_t)(k0 + k) * N + n0 + cc];
        tile[k * 65 + cc] = v.x; tile[k * 65 + cc + 1] = v.y;
        tile[k * 65 + cc + 2] = v.z; tile[k * 65 + cc + 3] = v.w;
    }
    __syncthreads();
    int rn = t >> 3, ck = (t & 7) * 8;
#pragma unroll
    for (int p = 0; p < 2; ++p) {
        int n = p * 32 + rn;
        v8s tv;
#pragma unroll
        for (int j = 0; j < 8; ++j) tv[j] = (short)f2bf(tile[(ck + j) * 65 + n]);
        *(v8s*)&out[(size_t)(n0 + n) * K + k0 + ck] = tv;
    }
}

// ------- prep_all: hidden cast (0..4095) + RoPE tab (4096..4607) + w_qkv^T (4608..10751) -------
__global__ __launch_bounds__(256) void prep_all_kernel(const float* __restrict__ hidden,
                                                       u16* __restrict__ hid_bf,
                                                       const int* __restrict__ positions,
                                                       float* __restrict__ cosT,
                                                       float* __restrict__ sinT,
                                                       const float* __restrict__ w_qkv,
                                                       u16* __restrict__ wqkv_t) {
    __shared__ float tile[64 * 65];
    int b = blockIdx.x;
    if (b < 4096) {
        size_t i = ((size_t)b * 256 + threadIdx.x) * 8;
        float4 a = *(const float4*)&hidden[i];
        float4 c = *(const float4*)&hidden[i + 4];
        v8s tv;
        tv[0] = (short)f2bf(a.x); tv[1] = (short)f2bf(a.y);
        tv[2] = (short)f2bf(a.z); tv[3] = (short)f2bf(a.w);
        tv[4] = (short)f2bf(c.x); tv[5] = (short)f2bf(c.y);
        tv[6] = (short)f2bf(c.z); tv[7] = (short)f2bf(c.w);
        *(v8s*)&hid_bf[i] = tv;
    } else if (b < 4608) {
        int idx = (b - 4096) * 256 + threadIdx.x;   // T*64 entries
        int tp = idx >> 6, i = idx & 63;
        float invf = exp2f(-(float)i * 0.31143075889569023f);  // log2(1e6)/64
        float f = (float)positions[tp] * invf;
        cosT[idx] = cosf(f);
        sinT[idx] = sinf(f);
    } else {
        int bx = b - 4608;                    // 96 x 64 tiles
        int n0 = (bx % 96) * 64, k0 = (bx / 96) * 64;
        transpose_tile64(w_qkv, wqkv_t, 4096, NQKV, n0, k0, tile, threadIdx.x);
    }
}

// ---------------- QKV GEMM (128x128 tile, fused QK-norm + RoPE epilogue) ----------------
// LDS staging XOR-swizzled: physical 16B-granule = logical ^ (row&7); the
// global SOURCE granule is permuted per lane (global_load_lds dest must stay
// lane*16), fragment ds_read_b128s then index granule^(l15&7) -> 2-way max.
__global__ __launch_bounds__(256) void gemm_qkv_kernel(
    const u16* __restrict__ A, const u16* __restrict__ Bt,
    const float* __restrict__ qw, const float* __restrict__ kw,
    const float* __restrict__ cosT, const float* __restrict__ sinT,
    u16* __restrict__ Qb, u16* __restrict__ Kb, u16* __restrict__ Vt)
{
    __shared__ __align__(16) u16 smem[16896];   // stage: A[128][64]+B[128][64]; epilogue: Ct[128][132]
    u16* As = smem;
    u16* Bs = smem + 8192;
    int tid = threadIdx.x;
    int wave = tid >> 6, lane = tid & 63;
    int quad = lane >> 4, l15 = lane & 15;
    int lm = l15 & 7;                 // read-side swizzle key
    int wm = wave >> 1, wn = wave & 1;
    int m0 = blockIdx.y * 128, n0 = blockIdx.x * 128;

    v4f acc[4][4];
    v4f z4 = {0.f, 0.f, 0.f, 0.f};
#pragma unroll
    for (int mi = 0; mi < 4; ++mi)
#pragma unroll
        for (int ni = 0; ni < 4; ++ni) acc[mi][ni] = z4;

    int rsub = lane >> 3;                       // row within 8-row chunk
    int cg = (lane & 7) ^ rsub;                 // swizzled source granule
    const u16* Ag = &A[(size_t)m0 * KD + cg * 8];
    const u16* Bg = &Bt[(size_t)n0 * KD + cg * 8];

    for (int k0 = 0; k0 < KD; k0 += 64) {
        __syncthreads();
#pragma unroll
        for (int c = 0; c < 4; ++c) {
            int ch = wave * 4 + c;
            int row = ch * 8 + rsub;
            gl2lds16(&Ag[(size_t)row * KD + k0], &As[ch * 512]);
            gl2lds16(&Bg[(size_t)row * KD + k0], &Bs[ch * 512]);
        }
        __syncthreads();
#pragma unroll
        for (int ks = 0; ks < 2; ++ks) {
            v8s af[4], bfr[4];
#pragma unroll
            for (int mi = 0; mi < 4; ++mi) {
                int ar = wm * 64 + mi * 16 + l15;
                af[mi] = *(const v8s*)&As[ar * 64 + ((((ks << 2) + quad) ^ lm) << 3)];
            }
#pragma unroll
            for (int ni = 0; ni < 4; ++ni) {
                int br = wn * 64 + ni * 16 + l15;
                bfr[ni] = *(const v8s*)&Bs[br * 64 + ((((ks << 2) + quad) ^ lm) << 3)];
            }
#pragma unroll
            for (int mi = 0; mi < 4; ++mi)
#pragma unroll
                for (int ni = 0; ni < 4; ++ni)
                    acc[mi][ni] = __builtin_amdgcn_mfma_f32_16x16x32_bf16(
                        af[mi], bfr[ni], acc[mi][ni], 0, 0, 0);
        }
    }

    // ---- fused epilogue: this block's 128 cols == one head ----
    __syncthreads();
    u16* Ct = smem;   // [128][132] bf16, padded stride
#pragma unroll
    for (int mi = 0; mi < 4; ++mi)
#pragma unroll
        for (int ni = 0; ni < 4; ++ni)
#pragma unroll
            for (int r = 0; r < 4; ++r)
                Ct[(wm * 64 + mi * 16 + quad * 4 + r) * 132 + wn * 64 + ni * 16 + l15] =
                    f2bf(acc[mi][ni][r]);
    __syncthreads();
    int head = blockIdx.x;    // 0..31 q, 32..39 k, 40..47 v
    int t0 = blockIdx.y * 128;
    if (head < 40) {
        if (tid < 128) {
            int row = tid;
            const float* w = (head < 32) ? qw : kw;
            float ss = 0.f;
            for (int i = 0; i < 128; ++i) {
                float x = bf2f(Ct[row * 132 + i]);
                ss += x * x;
            }
            float rs = rsqrtf(ss * (1.0f / 128.0f) + 1e-6f);
            if (head < 32) rs *= QSCALE;   // fold 1/sqrt(HD)*log2e into Q
            int ti = t0 + row;
            for (int i = 0; i < 64; ++i) {
                float x1 = bf2f(Ct[row * 132 + i]) * rs * w[i];
                float x2 = bf2f(Ct[row * 132 + 64 + i]) * rs * w[64 + i];
                float c = cosT[ti * 64 + i], s = sinT[ti * 64 + i];
                Ct[row * 132 + i]      = f2bf(x1 * c - x2 * s);
                Ct[row * 132 + 64 + i] = f2bf(x2 * c + x1 * s);
            }
        }
        __syncthreads();
        u16* dst = (head < 32) ? &Qb[((size_t)head * TT + t0) * HDM]
                               : &Kb[((size_t)(head - 32) * TT + t0) * HDM];
        for (int cix = tid; cix < 128 * 16; cix += 256) {
            int row = cix >> 4, part = (cix & 15) * 8;
            v8s tv;
#pragma unroll
            for (int j = 0; j < 8; ++j) tv[j] = (short)Ct[row * 132 + part + j];
            *(v8s*)&dst[row * HDM + part] = tv;
        }
    } else {
        // V head: write transposed Vt[kv][hd][t]
        int kvh = head - 40;
        if (tid < 128) {
            int hd = tid;
#pragma unroll
            for (int tb = 0; tb < 16; ++tb) {
                v8s tv;
#pragma unroll
                for (int j = 0; j < 8; ++j) tv[j] = (short)Ct[(tb * 8 + j) * 132 + hd];
                *(v8s*)&Vt[((size_t)kvh * HDM + hd) * TT + t0 + tb * 8] = tv;
            }
        }
    }
}

// ---------------- out-proj GEMM: 128x64 tiles, 1024 blocks (4/CU) ----------------
// C[2048,4096]fp32 = A[2048,4096]bf16 @ Bt[4096,4096]^T. Same swizzled staging.
__global__ __launch_bounds__(256) void gemm_o_kernel(
    const u16* __restrict__ A, const u16* __restrict__ Bt, float* __restrict__ C)
{
    __shared__ __align__(16) u16 smem[12288];   // A[128][64] + B[64][64]
    u16* As = smem;
    u16* Bs = smem + 8192;
    int tid = threadIdx.x;
    int wave = tid >> 6, lane = tid & 63;
    int quad = lane >> 4, l15 = lane & 15;
    int lm = l15 & 7;
    int wm = wave >> 1, wn = wave & 1;          // 2x2 waves: 64M x 32N each
    int m0 = blockIdx.y * 128, n0 = blockIdx.x * 64;

    v4f acc[4][2];
    v4f z4 = {0.f, 0.f, 0.f, 0.f};
#pragma unroll
    for (int mi = 0; mi < 4; ++mi)
#pragma unroll
        for (int ni = 0; ni < 2; ++ni) acc[mi][ni] = z4;

    int rsub = lane >> 3;
    int cg = (lane & 7) ^ rsub;
    const u16* Ag = &A[(size_t)m0 * KD + cg * 8];
    const u16* Bg = &Bt[(size_t)n0 * KD + cg * 8];

    for (int k0 = 0; k0 < KD; k0 += 64) {
        __syncthreads();
#pragma unroll
        for (int c = 0; c < 4; ++c) {           // A: 16 chunks of 8 rows
            int ch = wave * 4 + c;
            gl2lds16(&Ag[(size_t)(ch * 8 + rsub) * KD + k0], &As[ch * 512]);
        }
#pragma unroll
        for (int c = 0; c < 2; ++c) {           // B: 8 chunks of 8 rows
            int ch = wave * 2 + c;
            gl2lds16(&Bg[(size_t)(ch * 8 + rsub) * KD + k0], &Bs[ch * 512]);
        }
        __syncthreads();
#pragma unroll
        for (int ks = 0; ks < 2; ++ks) {
            v8s af[4], bfr[2];
#pragma unroll
            for (int mi = 0; mi < 4; ++mi) {
                int ar = wm * 64 + mi * 16 + l15;
                af[mi] = *(const v8s*)&As[ar * 64 + ((((ks << 2) + quad) ^ lm) << 3)];
            }
#pragma unroll
            for (int ni = 0; ni < 2; ++ni) {
                int br = wn * 32 + ni * 16 + l15;
                bfr[ni] = *(const v8s*)&Bs[br * 64 + ((((ks << 2) + quad) ^ lm) << 3)];
            }
#pragma unroll
            for (int mi = 0; mi < 4; ++mi)
#pragma unroll
                for (int ni = 0; ni < 2; ++ni)
                    acc[mi][ni] = __builtin_amdgcn_mfma_f32_16x16x32_bf16(
                        af[mi], bfr[ni], acc[mi][ni], 0, 0, 0);
        }
    }
#pragma unroll
    for (int mi = 0; mi < 4; ++mi)
#pragma unroll
        for (int ni = 0; ni < 2; ++ni)
#pragma unroll
            for (int r = 0; r < 4; ++r)
                C[(size_t)(m0 + wm * 64 + mi * 16 + quad * 4 + r) * DD +
                  (n0 + wn * 32 + ni * 16 + l15)] = acc[mi][ni][r];
}

// ------- attn (blocks 0..511) + w_o transpose backfill (512..4607) -------
// 128-row Q-tiles: 16 qb x 32 h; 4 waves x 32 q-rows (2 m-tiles of 16).
// K/V staged once per s-tile and reused by both m-tiles (half the staging of
// the 64-row version). Fixed-max softmax (S*log2e <= 16.34 < EOFF).
// Fully-masked waves skip compute. LDS XOR-swizzled. Longest-first order.
__global__ __launch_bounds__(256) void attn_plus_kernel(
    const u16* __restrict__ Qb, const u16* __restrict__ Kb,
    const u16* __restrict__ Vt, u16* __restrict__ Ob,
    const float* __restrict__ w_o, u16* __restrict__ wo_t)
{
    __shared__ __align__(16) char smem_raw[49152];
    int tid = threadIdx.x;
    if (blockIdx.x >= 512) {
        int bx = blockIdx.x - 512;            // 64 x 64 tiles
        int n0 = (bx & 63) * 64, k0 = (bx >> 6) * 64;
        transpose_tile64(w_o, wo_t, 4096, 4096, n0, k0, (float*)smem_raw, tid);
        return;
    }
    u16* Kl = (u16*)smem_raw;                  // [s=64][hd=128] swizzled, 16384 B
    u16* Vl = (u16*)(smem_raw + 16384);        // [hd=128][s=64] swizzled, 16384 B
    u16* Pl = (u16*)(smem_raw + 32768);        // per-wave P[32][64] swizzled, 16384 B
    int wave = tid >> 6, lane = tid & 63;
    int quad = lane >> 4, l15 = lane & 15;
    int idx = blockIdx.x;
    int h = idx & 31;
    int qb = 15 - (idx >> 5);        // longest blocks dispatch first
    int kv = h >> 2;                 // H/KV = 4
    int q0 = qb * 128;
    int rbase = q0 + wave * 32;      // this wave's first q-row
    int lm = l15 & 7;                // swizzle mask for this lane's row group

    v8s qf[2][4];
#pragma unroll
    for (int m = 0; m < 2; ++m) {
        const u16* qr = &Qb[((size_t)h * TT + rbase + m * 16 + l15) * HDM];
#pragma unroll
        for (int ks = 0; ks < 4; ++ks) qf[m][ks] = *(const v8s*)&qr[ks * 32 + quad * 8];
    }

    v4f z4 = {0.f, 0.f, 0.f, 0.f};
    v4f of[2][8];
#pragma unroll
    for (int m = 0; m < 2; ++m)
#pragma unroll
        for (int i = 0; i < 8; ++i) of[m][i] = z4;
    float lsum[2][4];
#pragma unroll
    for (int m = 0; m < 2; ++m)
#pragma unroll
        for (int r = 0; r < 4; ++r) lsum[m][r] = 0.f;
    u16* Pw = &Pl[wave * 2048];

    for (int s0 = 0; s0 <= q0 + 64; s0 += 64) {
        __syncthreads();
#pragma unroll
        for (int c = 0; c < 4; ++c) {
            int ch = wave * 4 + c;
            int rk = ch * 4 + (lane >> 4);              // Kl row (s-local)
            int ck = (lane & 15) ^ (rk & 7);            // logical chunk to fetch
            gl2lds16(&Kb[((size_t)kv * TT + s0 + rk) * HDM + ck * 8], &Kl[ch * 512]);
            int rv = ch * 8 + (lane >> 3);              // Vl row (hd)
            int cv = (lane & 7) ^ (rv & 7);
            gl2lds16(&Vt[((size_t)kv * HDM + rv) * TT + s0 + cv * 8], &Vl[ch * 512]);
        }
        __syncthreads();
        if (s0 > rbase + 31) continue;    // wave fully masked for this s-tile
        bool diag = (s0 + 63 > rbase);    // tile may cross this wave's diagonal
        // S = Q @ K^T; K-frags read once, reused by both m-tiles
        v4f sf[2][4];
#pragma unroll
        for (int nt = 0; nt < 4; ++nt) {
            v4f c0 = z4, c1 = z4;
#pragma unroll
            for (int ks = 0; ks < 4; ++ks) {
                v8s kf = *(const v8s*)&Kl[(nt * 16 + l15) * 128 + (((ks * 4 + quad) ^ lm) << 3)];
                c0 = __builtin_amdgcn_mfma_f32_16x16x32_bf16(qf[0][ks], kf, c0, 0, 0, 0);
                c1 = __builtin_amdgcn_mfma_f32_16x16x32_bf16(qf[1][ks], kf, c1, 0, 0, 0);
            }
            sf[0][nt] = c0;
            sf[1][nt] = c1;
        }
        if (diag) {   // causal mask only near the diagonal
#pragma unroll
            for (int m = 0; m < 2; ++m)
#pragma unroll
                for (int nt = 0; nt < 4; ++nt) {
                    int sg = s0 + nt * 16 + l15;
#pragma unroll
                    for (int r = 0; r < 4; ++r) {
                        int qg = rbase + m * 16 + quad * 4 + r;
                        if (sg > qg) sf[m][nt][r] = -3.0e38f;
                    }
                }
        }
        // fixed-max softmax + P write (C-layout -> swizzled A-layout in LDS)
#pragma unroll
        for (int m = 0; m < 2; ++m)
#pragma unroll
            for (int nt = 0; nt < 4; ++nt)
#pragma unroll
                for (int r = 0; r < 4; ++r) {
                    float p = exp2f(sf[m][nt][r] - EOFF);
                    lsum[m][r] += p;
                    int row = m * 16 + quad * 4 + r;
                    int pch = ((nt << 1) + (l15 >> 3)) ^ (row & 7);
                    Pw[row * 64 + pch * 8 + (l15 & 7)] = f2bf(p);
                }
        // O += P @ V; V-frags read once, reused by both m-tiles
#pragma unroll
        for (int sub = 0; sub < 2; ++sub) {
            int swz = (((sub << 2) + quad) ^ lm) << 3;
            v8s pa0 = *(const v8s*)&Pw[l15 * 64 + swz];
            v8s pa1 = *(const v8s*)&Pw[(16 + l15) * 64 + swz];
#pragma unroll
            for (int nt = 0; nt < 8; ++nt) {
                v8s vf = *(const v8s*)&Vl[(nt * 16 + l15) * 64 + swz];
                of[0][nt] = __builtin_amdgcn_mfma_f32_16x16x32_bf16(pa0, vf, of[0][nt], 0, 0, 0);
                of[1][nt] = __builtin_amdgcn_mfma_f32_16x16x32_bf16(pa1, vf, of[1][nt], 0, 0, 0);
            }
        }
    }
    // single end-of-kernel l reduction across the 16 col-lanes
#pragma unroll
    for (int off = 1; off < 16; off <<= 1)
#pragma unroll
        for (int m = 0; m < 2; ++m)
#pragma unroll
            for (int r = 0; r < 4; ++r) lsum[m][r] += __shfl_xor(lsum[m][r], off, 64);
#pragma unroll
    for (int m = 0; m < 2; ++m) {
        float invl[4];
#pragma unroll
        for (int r = 0; r < 4; ++r) invl[r] = 1.0f / lsum[m][r];
#pragma unroll
        for (int nt = 0; nt < 8; ++nt)
#pragma unroll
            for (int r = 0; r < 4; ++r)
                Ob[(size_t)(rbase + m * 16 + quad * 4 + r) * (NH * HDM) + h * HDM + nt * 16 + l15] =
                    f2bf(of[m][nt][r] * invl[r]);
    }
}

extern "C" void kernel_launch(void* const* d_in, const int* in_sizes, int n_in,
                              void* d_out, int out_size, void* d_ws, size_t ws_size,
                              hipStream_t stream)
{
    (void)in_sizes; (void)n_in; (void)out_size; (void)ws_size;
    const int*   positions = (const int*)d_in[0];
    const float* hidden    = (const float*)d_in[1];
    const float* w_qkv     = (const float*)d_in[2];
    const float* q_norm_w  = (const float*)d_in[3];
    const float* k_norm_w  = (const float*)d_in[4];
    const float* w_o       = (const float*)d_in[5];
    float* out = (float*)d_out;
    char* ws = (char*)d_ws;
    char* ob = (char*)d_out;

    // ---- d_ws layout (peak = 64 MiB exactly) ----
    u16* hid_bf = (u16*)(ws + 0);                 // [2048][4096] bf16      16 MiB
    u16* attnO  = (u16*)(ws + 0);                 // aliases hid_bf (dead after QKV GEMM)
    u16* wqkv_t = (u16*)(ws + (size_t)16777216);  // [6144][4096] bf16      50.33 MiB (ends at 64 MiB)
    u16* wo_t   = (u16*)(ws + (size_t)16777216);  // [4096][4096] bf16, overwrites wqkv_t after QKV GEMM

    // ---- d_out-hosted scratch (26.2 MiB <= 32 MiB; all dead before final GEMM) ----
    u16*   Qb   = (u16*)(ob + 0);                 // [32][2048][128]     16 MiB
    u16*   Kb   = (u16*)(ob + (size_t)16777216);  // [8][2048][128]      4 MiB
    u16*   Vt   = (u16*)(ob + (size_t)20971520);  // [8][128][2048]      4 MiB
    float* cosT = (float*)(ob + (size_t)25165824);// [2048][64]          0.5 MiB
    float* sinT = (float*)(ob + (size_t)25690112);// [2048][64]          0.5 MiB

    // hidden cast + RoPE tables + w_qkv transpose, one launch
    prep_all_kernel<<<10752, 256, 0, stream>>>(hidden, hid_bf, positions, cosT, sinT,
                                               w_qkv, wqkv_t);

    // single fused QKV GEMM (768 blocks = 3/CU)
    gemm_qkv_kernel<<<dim3(48, 16), 256, 0, stream>>>(
        hid_bf, wqkv_t, q_norm_w, k_norm_w, cosT, sinT, Qb, Kb, Vt);

    // attention (512 blocks, 128-row Q-tiles) + w_o transpose backfill (4096), one launch
    attn_plus_kernel<<<4608, 256, 0, stream>>>(Qb, Kb, Vt, attnO, w_o, wo_t);

    // out-proj GEMM: 128x64 tiles -> 1024 blocks = 4/CU
    gemm_o_kernel<<<dim3(64, 16), 256, 0, stream>>>(attnO, wo_t, out);
}